// Round 6
// baseline (501.723 us; speedup 1.0000x reference)
//
#include <hip/hip_runtime.h>
#include <hip/hip_bf16.h>
#include <stdint.h>

#define N_NODES 100000
#define N_EDGES 1000000
#define N_GRAPHS 512
#define HID 64
#define INN 32
#define INE 16
#define CPAD 32   // counters padded to 1 per 128 B line (atomic same-line serialization fix)

#define NPB 256                                // nodes per bucket
#define NBKT ((N_NODES + NPB - 1) / NPB)       // 391
#define BCAP 4096                              // per-bucket record capacity (mean 2560, 30 sigma headroom)

// ---- pre-converted MFMA weight-fragment slots (each slot = 64 lanes x bf8 = 1 KB) ----
#define S_NW0 0     // node w0   (K=32, NF=1)  4 slots
#define S_NW1 4     // node w1   (K=64, NF=2)  8 slots
#define S_EW0 12    // edge w0   (K=16, NF=1)  4 slots
#define S_EW1 16    // edge w1   (K=64, NF=2)  8 slots
#define S_CW0 24    // conv w0[l] l=0..2       8 slots each
#define S_CW1 48    // conv w1[l] l=0..2       8 slots each
#define S_LW0 72    // final w0                8 slots
#define S_LW1 80    // final w1                8 slots
#define NSLOT 88

typedef unsigned int uint32;
typedef unsigned short ushort16;
typedef __attribute__((ext_vector_type(8))) short bf8;
typedef __attribute__((ext_vector_type(4))) float f32x4;

__device__ __forceinline__ ushort16 f2bf(float f) {
    uint32 u = __float_as_uint(f);
    uint32 r = (u + 0x7fffu + ((u >> 16) & 1u)) >> 16;  // RNE
    return (ushort16)r;
}
__device__ __forceinline__ uint32 pack_bf2(float lo, float hi) {
    return (uint32)f2bf(lo) | ((uint32)f2bf(hi) << 16);
}
__device__ __forceinline__ float bf_lo(uint32 v) { return __uint_as_float(v << 16); }
__device__ __forceinline__ float bf_hi(uint32 v) { return __uint_as_float(v & 0xffff0000u); }

// ---- packed f16 message datapath (agg uses v_pk_* : 1 inst per 2 channels) ----
__device__ __forceinline__ uint32 pack_h2(float lo, float hi) {
    union { _Float16 h[2]; uint32 u; } cv;
    cv.h[0] = (_Float16)lo; cv.h[1] = (_Float16)hi;
    return cv.u;
}
__device__ __forceinline__ float h2_lo(uint32 v) {
    union { uint32 u; _Float16 h[2]; } cv; cv.u = v; return (float)cv.h[0];
}
__device__ __forceinline__ float h2_hi(uint32 v) {
    union { uint32 u; _Float16 h[2]; } cv; cv.u = v; return (float)cv.h[1];
}
__device__ __forceinline__ uint32 pk_add_f16(uint32 a, uint32 b) {
    uint32 r; asm("v_pk_add_f16 %0, %1, %2" : "=v"(r) : "v"(a), "v"(b)); return r;
}
__device__ __forceinline__ uint32 pk_max_f16(uint32 a, uint32 b) {
    uint32 r; asm("v_pk_max_f16 %0, %1, %2" : "=v"(r) : "v"(a), "v"(b)); return r;
}

// ---------------- diag ----------------

__global__ void k_diag(float* out, float val) { out[threadIdx.x] = val; }

// ---------------- weight fragment pre-conversion (runs once, 1 block) ----------------
// Fragment layout (verified R8/R9): value[j] = w[(f*32+quad*8+j)*HID + t*16+mn], 0 if k>=K.
// Slot s holds frag (t,f) with r = s-base = t*NF+f; storage [s][lane] = bf8 (4 uint32).

__global__ __launch_bounds__(256) void k_prep(
    const float* __restrict__ wn0, const float* __restrict__ wn1,
    const float* __restrict__ we0, const float* __restrict__ we1,
    const float* __restrict__ cw0, const float* __restrict__ cw1,
    const float* __restrict__ lw0, const float* __restrict__ lw1,
    uint32* __restrict__ wfrag)
{
    for (int idx = threadIdx.x; idx < NSLOT * 64; idx += 256) {
        int s = idx >> 6, lane = idx & 63;
        const float* w; int K, NF, base;
        if (s < 4)       { w = wn0; K = 32; NF = 1; base = S_NW0; }
        else if (s < 12) { w = wn1; K = 64; NF = 2; base = S_NW1; }
        else if (s < 16) { w = we0; K = 16; NF = 1; base = S_EW0; }
        else if (s < 24) { w = we1; K = 64; NF = 2; base = S_EW1; }
        else if (s < 48) { int l = (s - S_CW0) >> 3; w = cw0 + l * 4096; K = 64; NF = 2; base = S_CW0 + l * 8; }
        else if (s < 72) { int l = (s - S_CW1) >> 3; w = cw1 + l * 4096; K = 64; NF = 2; base = S_CW1 + l * 8; }
        else if (s < 80) { w = lw0; K = 64; NF = 2; base = S_LW0; }
        else             { w = lw1; K = 64; NF = 2; base = S_LW1; }
        int r = s - base, t = r / NF, f = r - t * NF;
        int quad = lane >> 4, mn = lane & 15;
        uint32 out[4];
        #pragma unroll
        for (int p = 0; p < 4; p++) {
            int k0 = f * 32 + quad * 8 + p * 2;
            float lo = (k0 < K)     ? w[(size_t)k0 * HID + t * 16 + mn]       : 0.f;
            float hi = (k0 + 1 < K) ? w[(size_t)(k0 + 1) * HID + t * 16 + mn] : 0.f;
            out[p] = pack_bf2(lo, hi);
        }
        *(uint4*)(wfrag + (size_t)idx * 4) = make_uint4(out[0], out[1], out[2], out[3]);
    }
}

// ---------------- CSR build via 2-level bucket partition ----------------

__global__ __launch_bounds__(256) void k_binA(const int* __restrict__ src,
                                              const int* __restrict__ dst,
                                              int* __restrict__ bcursor,
                                              uint2* __restrict__ binned) {
    __shared__ int cnt[NBKT];
    __shared__ int cur[NBKT];
    const int t = threadIdx.x;
    for (int b = t; b < NBKT; b += 256) cnt[b] = 0;
    __syncthreads();
    const int base = blockIdx.x * 4096;
    #pragma unroll
    for (int j = 0; j < 16; j++) {
        int e = base + j * 256 + t;
        if (e < N_EDGES) atomicAdd(&cnt[dst[e] >> 8], 1);
    }
    __syncthreads();
    for (int b = t; b < NBKT; b += 256) {
        int c = cnt[b];
        cur[b] = (c > 0) ? atomicAdd(&bcursor[(size_t)b * CPAD], c) : 0;
    }
    __syncthreads();
    #pragma unroll
    for (int j = 0; j < 16; j++) {
        int e = base + j * 256 + t;
        if (e < N_EDGES) {
            int d = dst[e];
            int bkt = d >> 8;
            int r = atomicAdd(&cur[bkt], 1);
            if (r < BCAP)
                binned[(size_t)bkt * BCAP + r] =
                    make_uint2((uint32)src[e] | ((uint32)(d & (NPB - 1)) << 17), (uint32)e);
        }
    }
}

__global__ __launch_bounds__(512) void k_scanB(const int* __restrict__ bcursor,
                                               int* __restrict__ bbase) {
    __shared__ int sh[512];
    const int t = threadIdx.x;
    int v = (t < NBKT) ? min(bcursor[(size_t)t * CPAD], BCAP) : 0;
    sh[t] = v; __syncthreads();
    for (int off = 1; off < 512; off <<= 1) {
        int u = (t >= off) ? sh[t - off] : 0;
        __syncthreads();
        sh[t] += u;
        __syncthreads();
    }
    if (t < NBKT) bbase[t] = sh[t] - v;  // exclusive
}

__global__ __launch_bounds__(256) void k_bucketB(const int* __restrict__ bcursor,
                                                 const int* __restrict__ bbase,
                                                 const uint2* __restrict__ binned,
                                                 int* __restrict__ rowptr,
                                                 int* __restrict__ perm_src,
                                                 int* __restrict__ eperm) {
    __shared__ int cnt[NPB];
    __shared__ int sh[NPB];
    const int b = blockIdx.x, t = threadIdx.x;
    const int n = min(bcursor[(size_t)b * CPAD], BCAP);
    const int base = bbase[b];
    const uint2* brec = binned + (size_t)b * BCAP;
    cnt[t] = 0;
    __syncthreads();
    for (int i = t; i < n; i += 256)
        atomicAdd(&cnt[brec[i].x >> 17], 1);
    __syncthreads();
    int c = cnt[t];
    sh[t] = c; __syncthreads();
    for (int off = 1; off < NPB; off <<= 1) {
        int u = (t >= off) ? sh[t - off] : 0;
        __syncthreads();
        sh[t] += u;
        __syncthreads();
    }
    int excl = sh[t] - c;
    int g = b * NPB + t;
    if (g < N_NODES) rowptr[g] = base + excl;
    if (b == 0 && t == 0) rowptr[N_NODES] = N_EDGES;
    cnt[t] = excl;  // becomes per-node cursor
    __syncthreads();
    for (int i = t; i < n; i += 256) {
        uint2 r = brec[i];
        int dl = (int)(r.x >> 17);
        int p = base + atomicAdd(&cnt[dl], 1);
        perm_src[p] = (int)(r.x & 0x1FFFFu);
        eperm[p] = (int)r.y;
    }
}

// ---------------- node init MLP2 via MFMA (f32 input) ----------------
// Per-wave LDS tile -> no __syncthreads needed (DS ops of a wave are in-order).
// out_bf is packed f16 (agg datapath); MFMA internals stay bf16.

template<int NF, bool RELU_RES, bool BF_IN>
__global__ __launch_bounds__(256, 4) void k_mlp_mfma(
    const void* __restrict__ in, const float* __restrict__ hprev, float* __restrict__ out,
    const uint32* __restrict__ wf0, const float* __restrict__ b0,
    const uint32* __restrict__ wf1, const float* __restrict__ b1,
    uint32* __restrict__ out_bf, int nrows)
{
    __shared__ ushort tile[4][16 * 72];
    const int wave = threadIdx.x >> 6, lane = threadIdx.x & 63;
    const int quad = lane >> 4, mn = lane & 15;
    ushort* T = &tile[wave][0];

    bf8 w0f[4][NF];
    #pragma unroll
    for (int t = 0; t < 4; t++)
        #pragma unroll
        for (int f = 0; f < NF; f++)
            w0f[t][f] = *(const bf8*)(wf0 + ((size_t)(t * NF + f) * 64 + lane) * 4);
    bf8 w1f[4][2];
    #pragma unroll
    for (int t = 0; t < 4; t++)
        #pragma unroll
        for (int f = 0; f < 2; f++)
            w1f[t][f] = *(const bf8*)(wf1 + ((size_t)(t * 2 + f) * 64 + lane) * 4);
    float b0v[4], b1v[4];
    #pragma unroll
    for (int t = 0; t < 4; t++) { b0v[t] = b0[t*16+mn]; b1v[t] = b1[t*16+mn]; }

    const int ebase = blockIdx.x * 64 + wave * 16;  // this wave's 16 rows
    int rowA = ebase + mn; if (rowA > nrows - 1) rowA = nrows - 1;
    bf8 a1[NF];
    if (BF_IN) {
        const ushort* row = (const ushort*)in + (size_t)rowA * HID;
        #pragma unroll
        for (int f = 0; f < NF; f++)
            a1[f] = *(const bf8*)(row + f * 32 + quad * 8);
    } else {
        const float* inf = (const float*)in;
        #pragma unroll
        for (int f = 0; f < NF; f++) {
            const float4* pr = (const float4*)(inf + (size_t)rowA * (NF * 32) + f * 32 + quad * 8);
            float4 v0 = pr[0], v1 = pr[1];
            a1[f][0]=(short)f2bf(v0.x); a1[f][1]=(short)f2bf(v0.y);
            a1[f][2]=(short)f2bf(v0.z); a1[f][3]=(short)f2bf(v0.w);
            a1[f][4]=(short)f2bf(v1.x); a1[f][5]=(short)f2bf(v1.y);
            a1[f][6]=(short)f2bf(v1.z); a1[f][7]=(short)f2bf(v1.w);
        }
    }
    // layer1 -> LDS (bf16, A-ready layout)
    #pragma unroll
    for (int t = 0; t < 4; t++) {
        f32x4 c = {0.f, 0.f, 0.f, 0.f};
        #pragma unroll
        for (int f = 0; f < NF; f++)
            c = __builtin_amdgcn_mfma_f32_16x16x32_bf16(a1[f], w0f[t][f], c, 0, 0, 0);
        #pragma unroll
        for (int rg = 0; rg < 4; rg++) {
            int row = quad * 4 + rg;
            T[row * 72 + t * 16 + mn] = f2bf(fmaxf(c[rg] + b0v[t], 0.f));
        }
    }
    __builtin_amdgcn_wave_barrier();
    bf8 a2[2];
    #pragma unroll
    for (int f = 0; f < 2; f++)
        a2[f] = *(const bf8*)&T[mn * 72 + f * 32 + quad * 8];
    // layer2 + epilogue: f32 direct store, bf16 back to LDS
    #pragma unroll
    for (int t = 0; t < 4; t++) {
        f32x4 c = {0.f, 0.f, 0.f, 0.f};
        c = __builtin_amdgcn_mfma_f32_16x16x32_bf16(a2[0], w1f[t][0], c, 0, 0, 0);
        c = __builtin_amdgcn_mfma_f32_16x16x32_bf16(a2[1], w1f[t][1], c, 0, 0, 0);
        #pragma unroll
        for (int rg = 0; rg < 4; rg++) {
            int row = quad * 4 + rg;
            int rowg = ebase + row;
            int rowc = (rowg < nrows) ? rowg : (nrows - 1);
            float v = c[rg] + b1v[t];
            if (RELU_RES) {
                float hv = hprev[(size_t)rowc * HID + t * 16 + mn];
                v = fmaxf(v + hv, 0.f);
            }
            if (rowg < nrows) out[(size_t)rowg * HID + t * 16 + mn] = v;
            T[row * 72 + t * 16 + mn] = f2bf(v);
        }
    }
    if (out_bf) {
        __builtin_amdgcn_wave_barrier();
        int half = lane >> 5, c32 = lane & 31;
        #pragma unroll
        for (int rr = 0; rr < 8; rr++) {
            int row = rr * 2 + half;
            int pos = ebase + row;
            if (pos < nrows) {
                uint32 w = *(const uint32*)&T[row * 72 + c32 * 2];
                out_bf[(size_t)pos * 32 + c32] = pack_h2(bf_lo(w), bf_hi(w));
            }
        }
    }
}

// ---------------- edge MLP2 via MFMA: wave-independent 16-row tiles, ----------------
// 2-deep pipelined gather (eattr for t+s, eperm index for t+2s), no barriers.
// (256,4): 48 VGPR fits without spills -- (256,8) forced 32 VGPR and spilled
// weight frags to scratch (R4: FETCH 63->338 MB, 57->161 us). Do not raise.
// e_sorted output is packed f16 (agg datapath).

__global__ __launch_bounds__(256, 4) void k_edge_mlp_mfma(
    const float* __restrict__ eattr, const int* __restrict__ eperm,
    uint32* __restrict__ e_sorted, const uint32* __restrict__ wfrag,
    const float* __restrict__ b0, const float* __restrict__ b1)
{
    __shared__ ushort tile[4][16 * 72];  // per-wave 16 rows x 64 bf16 (+8 pad)
    const int wave = threadIdx.x >> 6, lane = threadIdx.x & 63;
    const int quad = lane >> 4, mn = lane & 15;
    ushort* T = &tile[wave][0];

    bf8 w0f[4];      // layer1 B-frags (K=16 zero-padded, NF=1)
    #pragma unroll
    for (int t = 0; t < 4; t++)
        w0f[t] = *(const bf8*)(wfrag + ((size_t)(S_EW0 + t) * 64 + lane) * 4);
    bf8 w1f[4][2];
    #pragma unroll
    for (int t = 0; t < 4; t++)
        #pragma unroll
        for (int f = 0; f < 2; f++)
            w1f[t][f] = *(const bf8*)(wfrag + ((size_t)(S_EW1 + t * 2 + f) * 64 + lane) * 4);
    float b0v[4], b1v[4];
    #pragma unroll
    for (int t = 0; t < 4; t++) { b0v[t] = b0[t*16+mn]; b1v[t] = b1[t*16+mn]; }

    const int nT = N_EDGES / 16;  // 62500 (exact)
    const int stride = gridDim.x * 4;
    int t = blockIdx.x * 4 + wave;

    // pipeline state: va/vb = eattr row for tile t; ep1 = edge id for tile t+stride
    int ep0 = (t < nT) ? eperm[t * 16 + mn] : 0;
    int ep1 = (t + stride < nT) ? eperm[(t + stride) * 16 + mn] : 0;
    float4 va = make_float4(0.f,0.f,0.f,0.f), vb = va;
    if (quad < 2 && t < nT) {
        const float4* pr = (const float4*)(eattr + (size_t)ep0 * INE + quad * 8);
        va = pr[0]; vb = pr[1];
    }

    for (; t < nT; t += stride) {
        const int tn = t + stride;
        float4 na = make_float4(0.f,0.f,0.f,0.f), nb = na;
        if (quad < 2 && tn < nT) {
            const float4* pr = (const float4*)(eattr + (size_t)ep1 * INE + quad * 8);
            na = pr[0]; nb = pr[1];
        }
        int ep2 = (t + 2 * stride < nT) ? eperm[(t + 2 * stride) * 16 + mn] : 0;

        bf8 a1 = {};
        if (quad < 2) {
            a1[0]=(short)f2bf(va.x); a1[1]=(short)f2bf(va.y);
            a1[2]=(short)f2bf(va.z); a1[3]=(short)f2bf(va.w);
            a1[4]=(short)f2bf(vb.x); a1[5]=(short)f2bf(vb.y);
            a1[6]=(short)f2bf(vb.z); a1[7]=(short)f2bf(vb.w);
        }
        #pragma unroll
        for (int t4 = 0; t4 < 4; t4++) {
            f32x4 c = {0.f, 0.f, 0.f, 0.f};
            c = __builtin_amdgcn_mfma_f32_16x16x32_bf16(a1, w0f[t4], c, 0, 0, 0);
            #pragma unroll
            for (int rg = 0; rg < 4; rg++) {
                int row = quad * 4 + rg;
                T[row * 72 + t4 * 16 + mn] = f2bf(fmaxf(c[rg] + b0v[t4], 0.f));
            }
        }
        __builtin_amdgcn_wave_barrier();
        bf8 a2[2];
        #pragma unroll
        for (int f = 0; f < 2; f++)
            a2[f] = *(const bf8*)&T[mn * 72 + f * 32 + quad * 8];
        #pragma unroll
        for (int t4 = 0; t4 < 4; t4++) {
            f32x4 c = {0.f, 0.f, 0.f, 0.f};
            c = __builtin_amdgcn_mfma_f32_16x16x32_bf16(a2[0], w1f[t4][0], c, 0, 0, 0);
            c = __builtin_amdgcn_mfma_f32_16x16x32_bf16(a2[1], w1f[t4][1], c, 0, 0, 0);
            #pragma unroll
            for (int rg = 0; rg < 4; rg++) {
                int row = quad * 4 + rg;
                T[row * 72 + t4 * 16 + mn] = f2bf(c[rg] + b1v[t4]);
            }
        }
        __builtin_amdgcn_wave_barrier();
        int half = lane >> 5, c32 = lane & 31;
        #pragma unroll
        for (int rr = 0; rr < 8; rr++) {
            int row = rr * 2 + half;
            uint32 w = *(const uint32*)&T[row * 72 + c32 * 2];
            e_sorted[((size_t)t * 16 + row) * 32 + c32] = pack_h2(bf_lo(w), bf_hi(w));
        }
        __builtin_amdgcn_wave_barrier();
        va = na; vb = nb; ep1 = ep2;
    }
}

// ---------------- fused GINE layer: agg (64 nodes/block) + MLP2 via MFMA ----------------
// Agg datapath is packed f16: hv/ev are 2 channels per uint32; message =
// pk_max(pk_add(hv,ev),0); accumulate with pk_add (deg~10, values O(1) ->
// f16 accumulation error ~1e-2 << 0.5 tolerance). z -> LDS in bf16 A-frag
// layout for the MFMA MLP. h (f32) owned by block -> in-place; h_f16 ping-pong.

template<bool RELU_RES, bool BF_OUT>
__global__ __launch_bounds__(256, 4) void k_layer(
    float* __restrict__ h, const uint32* __restrict__ bf_in,
    uint32* __restrict__ bf_out, const uint32* __restrict__ e_sorted,
    const int* __restrict__ rowptr, const int* __restrict__ perm_src,
    const uint32* __restrict__ wf0, const float* __restrict__ b0,
    const uint32* __restrict__ wf1, const float* __restrict__ b1)
{
    __shared__ ushort tile[4][16 * 72];
    const int wave = threadIdx.x >> 6, lane = threadIdx.x & 63;
    const int quad = lane >> 4, mn = lane & 15;
    const int half = lane >> 5, c = lane & 31;
    ushort* T = &tile[wave][0];

    const int nbase = blockIdx.x * 64 + wave * 16;  // this wave's 16 nodes
    const uint32 zero2 = 0u;

    // ---- Phase A: aggregation for the wave's 16 nodes -> z into LDS (A-frag layout) ----
    int rp = rowptr[min(nbase + (int)lane, N_NODES)];  // lane-parallel fence fetch
    #pragma unroll 1
    for (int i = 0; i < 16; i++) {
        int r0 = __shfl(rp, i), r1 = __shfl(rp, i + 1);
        int nodec = min(nbase + i, N_NODES - 1);
        const float2 hn = *(const float2*)&h[(size_t)nodec * HID + 2 * c];
        uint32 acc = zero2;
        #pragma unroll 1
        for (int base = r0; base < r1; base += 16) {
            int idxs[8]; int sidx[8];
            #pragma unroll
            for (int j = 0; j < 8; j++) {
                int idx = base + 2 * j + half;
                idxs[j] = idx;
                int idxc = (idx < r1) ? idx : (r1 - 1);
                sidx[j] = perm_src[idxc];
            }
            uint32 hv[8], ev[8];
            #pragma unroll
            for (int j = 0; j < 8; j++) {
                int idxc = (idxs[j] < r1) ? idxs[j] : (r1 - 1);
                hv[j] = bf_in[(size_t)sidx[j] * 32 + c];
                ev[j] = e_sorted[(size_t)idxc * 32 + c];
            }
            #pragma unroll
            for (int j = 0; j < 8; j++) {
                uint32 m = pk_max_f16(pk_add_f16(hv[j], ev[j]), zero2);
                m = (idxs[j] < r1) ? m : 0u;
                acc = pk_add_f16(acc, m);
            }
        }
        float accx = h2_lo(acc), accy = h2_hi(acc);
        accx += __shfl_xor(accx, 32);
        accy += __shfl_xor(accy, 32);
        if (half == 0)
            *(uint32*)&T[i * 72 + 2 * c] = pack_bf2(fmaf(1.1f, hn.x, accx),
                                                    fmaf(1.1f, hn.y, accy));
    }
    __builtin_amdgcn_wave_barrier();

    // ---- Phase B: MLP. Weight frags loaded here (after agg) to cap peak VGPR. ----
    bf8 w0f[4][2], w1f[4][2];
    #pragma unroll
    for (int t = 0; t < 4; t++)
        #pragma unroll
        for (int f = 0; f < 2; f++) {
            w0f[t][f] = *(const bf8*)(wf0 + ((size_t)(t * 2 + f) * 64 + lane) * 4);
            w1f[t][f] = *(const bf8*)(wf1 + ((size_t)(t * 2 + f) * 64 + lane) * 4);
        }
    float b0v[4], b1v[4];
    #pragma unroll
    for (int t = 0; t < 4; t++) { b0v[t] = b0[t*16+mn]; b1v[t] = b1[t*16+mn]; }

    bf8 a1[2];
    #pragma unroll
    for (int f = 0; f < 2; f++)
        a1[f] = *(const bf8*)&T[mn * 72 + f * 32 + quad * 8];
    #pragma unroll
    for (int t = 0; t < 4; t++) {
        f32x4 cc = {0.f, 0.f, 0.f, 0.f};
        cc = __builtin_amdgcn_mfma_f32_16x16x32_bf16(a1[0], w0f[t][0], cc, 0, 0, 0);
        cc = __builtin_amdgcn_mfma_f32_16x16x32_bf16(a1[1], w0f[t][1], cc, 0, 0, 0);
        #pragma unroll
        for (int rg = 0; rg < 4; rg++) {
            int row = quad * 4 + rg;
            T[row * 72 + t * 16 + mn] = f2bf(fmaxf(cc[rg] + b0v[t], 0.f));
        }
    }
    __builtin_amdgcn_wave_barrier();
    bf8 a2[2];
    #pragma unroll
    for (int f = 0; f < 2; f++)
        a2[f] = *(const bf8*)&T[mn * 72 + f * 32 + quad * 8];
    #pragma unroll
    for (int t = 0; t < 4; t++) {
        f32x4 cc = {0.f, 0.f, 0.f, 0.f};
        cc = __builtin_amdgcn_mfma_f32_16x16x32_bf16(a2[0], w1f[t][0], cc, 0, 0, 0);
        cc = __builtin_amdgcn_mfma_f32_16x16x32_bf16(a2[1], w1f[t][1], cc, 0, 0, 0);
        #pragma unroll
        for (int rg = 0; rg < 4; rg++) {
            int row = quad * 4 + rg;
            int rowg = nbase + row;
            int rowc = (rowg < N_NODES) ? rowg : (N_NODES - 1);
            float v = cc[rg] + b1v[t];
            if (RELU_RES) {
                float hv = h[(size_t)rowc * HID + t * 16 + mn];
                v = fmaxf(v + hv, 0.f);
            }
            if (rowg < N_NODES) h[(size_t)rowg * HID + t * 16 + mn] = v;
            T[row * 72 + t * 16 + mn] = f2bf(v);
        }
    }
    if (BF_OUT) {
        __builtin_amdgcn_wave_barrier();
        #pragma unroll
        for (int rr = 0; rr < 8; rr++) {
            int row = rr * 2 + half;
            int pos = nbase + row;
            if (pos < N_NODES) {
                uint32 w = *(const uint32*)&T[row * 72 + c * 2];
                bf_out[(size_t)pos * 32 + c] = pack_h2(bf_lo(w), bf_hi(w));
            }
        }
    }
}

// ---------------- global add pool (batch is sorted) ----------------

__global__ __launch_bounds__(256) void k_pool(
    const float* __restrict__ h, const int* __restrict__ batch, float* __restrict__ out)
{
    int g = blockIdx.x;
    int lane = threadIdx.x & 63, wave = threadIdx.x >> 6;
    int lo = 0, hi = N_NODES;
    while (lo < hi) { int mid = (lo + hi) >> 1; if (batch[mid] < g) lo = mid + 1; else hi = mid; }
    int start = lo;
    hi = N_NODES;
    while (lo < hi) { int mid = (lo + hi) >> 1; if (batch[mid] < g + 1) lo = mid + 1; else hi = mid; }
    int end = lo;
    float acc = 0.f;
    for (int n = start + wave; n < end; n += 4)
        acc += h[(size_t)n*HID + lane];
    __shared__ float sh[4][64];
    sh[wave][lane] = acc;
    __syncthreads();
    if (wave == 0)
        out[(size_t)g*HID + lane] = sh[0][lane] + sh[1][lane] + sh[2][lane] + sh[3][lane];
}

// ---------------- launch ----------------

extern "C" void kernel_launch(void* const* d_in, const int* in_sizes, int n_in,
                              void* d_out, int out_size, void* d_ws, size_t ws_size,
                              hipStream_t stream) {
    const float* x     = (const float*)d_in[0];
    const int*   eidx  = (const int*)  d_in[1];
    const float* eattr = (const float*)d_in[2];
    const int*   batch = (const int*)  d_in[3];
    const float* wn0 = (const float*)d_in[4];  const float* bn0 = (const float*)d_in[5];
    const float* wn1 = (const float*)d_in[6];  const float* bn1 = (const float*)d_in[7];
    const float* we0 = (const float*)d_in[8];  const float* be0 = (const float*)d_in[9];
    const float* we1 = (const float*)d_in[10]; const float* be1 = (const float*)d_in[11];
    const float* cw0 = (const float*)d_in[12]; const float* cb0 = (const float*)d_in[13];
    const float* cw1 = (const float*)d_in[14]; const float* cb1 = (const float*)d_in[15];
    const float* lw0 = (const float*)d_in[16]; const float* lb0 = (const float*)d_in[17];
    const float* lw1 = (const float*)d_in[18]; const float* lb1 = (const float*)d_in[19];
    const int* src = eidx;
    const int* dst = eidx + N_EDGES;

    // workspace layout (~200 MB)
    char* ws = (char*)d_ws;
    size_t off = 0;
    auto alloc = [&](size_t bytes) -> void* {
        void* p = ws + off;
        off = (off + bytes + 255) & ~(size_t)255;
        return p;
    };
    int*    bcursor  = (int*)  alloc((size_t)NBKT * CPAD * 4);       // per-bucket claim cursors / counts
    int*    bbase    = (int*)  alloc((size_t)NBKT * 4);              // bucket slot bases (exclusive scan)
    uint2*  binned   = (uint2*)alloc((size_t)NBKT * BCAP * 8);       // 12.8 MB bucket-partitioned records
    int*    rowptr   = (int*)  alloc((size_t)(N_NODES + 1) * 4);
    int*    perm_src = (int*)  alloc((size_t)N_EDGES * 4);
    int*    eperm    = (int*)  alloc((size_t)N_EDGES * 4);           // slot -> original edge id
    float*  h        = (float*)alloc((size_t)N_NODES * HID * 4);
    uint32* bfB      = (uint32*)alloc((size_t)N_NODES * 32 * 4);     // f16 h ping-pong B
    uint32* bfA      = (uint32*)alloc((size_t)N_NODES * 32 * 4);     // f16 h ping-pong A
    uint32* e_sorted = (uint32*)alloc((size_t)N_EDGES * HID * 2);
    uint32* wfrag    = (uint32*)alloc((size_t)NSLOT * 64 * 16);      // pre-converted weight frags
    if (off > ws_size) {
        k_diag<<<1, 64, 0, stream>>>((float*)d_out, 1.0e9f);
        return;
    }

    // weight fragment pre-conversion (independent of everything else)
    k_prep<<<1, 256, 0, stream>>>(wn0, wn1, we0, we1, cw0, cw1, lw0, lw1, wfrag);

    // CSR build: bucket partition
    hipMemsetAsync(bcursor, 0, (size_t)NBKT * CPAD * 4, stream);
    k_binA<<<(N_EDGES + 4095) / 4096, 256, 0, stream>>>(src, dst, bcursor, binned);
    k_scanB<<<1, 512, 0, stream>>>(bcursor, bbase);
    k_bucketB<<<NBKT, 256, 0, stream>>>(bcursor, bbase, binned, rowptr, perm_src, eperm);

    const int MGRID = (N_NODES + 63) / 64;  // 1563

    // node init MLP: x (f32) -> h (+ f16 copy into bfA)
    k_mlp_mfma<1, false, false><<<MGRID, 256, 0, stream>>>(
        x, nullptr, h, wfrag + S_NW0 * 256, bn0, wfrag + S_NW1 * 256, bn1, bfA, N_NODES);

    // edge MLP via MFMA -> e_sorted (dst-sorted order, f16); gathers eattr via eperm
    k_edge_mlp_mfma<<<2048, 256, 0, stream>>>(eattr, eperm, e_sorted, wfrag, be0, be1);

    // 3 residual conv layers (fused agg+MLP), f16 ping-pong A->B->A->B
    k_layer<true, true><<<MGRID, 256, 0, stream>>>(
        h, bfA, bfB, e_sorted, rowptr, perm_src,
        wfrag + (S_CW0 + 0 * 8) * 256, cb0 + 0 * 64, wfrag + (S_CW1 + 0 * 8) * 256, cb1 + 0 * 64);
    k_layer<true, true><<<MGRID, 256, 0, stream>>>(
        h, bfB, bfA, e_sorted, rowptr, perm_src,
        wfrag + (S_CW0 + 1 * 8) * 256, cb0 + 1 * 64, wfrag + (S_CW1 + 1 * 8) * 256, cb1 + 1 * 64);
    k_layer<true, true><<<MGRID, 256, 0, stream>>>(
        h, bfA, bfB, e_sorted, rowptr, perm_src,
        wfrag + (S_CW0 + 2 * 8) * 256, cb0 + 2 * 64, wfrag + (S_CW1 + 2 * 8) * 256, cb1 + 2 * 64);
    // final GINE conv (no residual/relu, no bf output)
    k_layer<false, false><<<MGRID, 256, 0, stream>>>(
        h, bfB, bfA, e_sorted, rowptr, perm_src,
        wfrag + S_LW0 * 256, lb0, wfrag + S_LW1 * 256, lb1);

    // global add pool
    k_pool<<<N_GRAPHS, 256, 0, stream>>>(h, batch, (float*)d_out);
}

// Round 7
// 459.581 us; speedup vs baseline: 1.0917x; 1.0917x over previous
//
#include <hip/hip_runtime.h>
#include <hip/hip_bf16.h>
#include <stdint.h>

#define N_NODES 100000
#define N_EDGES 1000000
#define N_GRAPHS 512
#define HID 64
#define INN 32
#define INE 16
#define CPAD 32   // counters padded to 1 per 128 B line (atomic same-line serialization fix)

#define NPB 256                                // nodes per bucket
#define NBKT ((N_NODES + NPB - 1) / NPB)       // 391
#define BCAP 4096                              // per-bucket record capacity (mean 2560, 30 sigma headroom)
#define NBB  ((N_EDGES + 4095) / 4096)         // 245 binA blocks
#define PMCAP 320                              // per-wave LDS perm_src stage (mean 160, +12.6 sigma)

// ---- pre-converted MFMA weight-fragment slots (each slot = 64 lanes x bf8 = 1 KB) ----
#define S_NW0 0     // node w0   (K=32, NF=1)  4 slots
#define S_NW1 4     // node w1   (K=64, NF=2)  8 slots
#define S_EW0 12    // edge w0   (K=16, NF=1)  4 slots
#define S_EW1 16    // edge w1   (K=64, NF=2)  8 slots
#define S_CW0 24    // conv w0[l] l=0..2       8 slots each
#define S_CW1 48    // conv w1[l] l=0..2       8 slots each
#define S_LW0 72    // final w0                8 slots
#define S_LW1 80    // final w1                8 slots
#define NSLOT 88

typedef unsigned int uint32;
typedef unsigned short ushort16;
typedef __attribute__((ext_vector_type(8))) short bf8;
typedef __attribute__((ext_vector_type(4))) float f32x4;

__device__ __forceinline__ ushort16 f2bf(float f) {
    uint32 u = __float_as_uint(f);
    uint32 r = (u + 0x7fffu + ((u >> 16) & 1u)) >> 16;  // RNE
    return (ushort16)r;
}
__device__ __forceinline__ uint32 pack_bf2(float lo, float hi) {
    return (uint32)f2bf(lo) | ((uint32)f2bf(hi) << 16);
}
__device__ __forceinline__ float bf_lo(uint32 v) { return __uint_as_float(v << 16); }
__device__ __forceinline__ float bf_hi(uint32 v) { return __uint_as_float(v & 0xffff0000u); }

// ---- packed f16 message datapath (agg uses v_pk_* : 1 inst per 2 channels) ----
__device__ __forceinline__ unsigned short f2h_u(float f) {
    union { _Float16 h; unsigned short u; } cv; cv.h = (_Float16)f; return cv.u;
}
__device__ __forceinline__ float h2_lo(uint32 v) {
    union { uint32 u; _Float16 h[2]; } cv; cv.u = v; return (float)cv.h[0];
}
__device__ __forceinline__ float h2_hi(uint32 v) {
    union { uint32 u; _Float16 h[2]; } cv; cv.u = v; return (float)cv.h[1];
}
__device__ __forceinline__ uint32 pk_add_f16(uint32 a, uint32 b) {
    uint32 r; asm("v_pk_add_f16 %0, %1, %2" : "=v"(r) : "v"(a), "v"(b)); return r;
}
__device__ __forceinline__ uint32 pk_max_f16(uint32 a, uint32 b) {
    uint32 r; asm("v_pk_max_f16 %0, %1, %2" : "=v"(r) : "v"(a), "v"(b)); return r;
}

// ---------------- diag ----------------

__global__ void k_diag(float* out, float val) { out[threadIdx.x] = val; }

// ---------------- merged kernel 1: binA (blocks 0..244) | weight prep (block 245) ----------------
// Fragment layout (verified R8/R9): value[j] = w[(f*32+quad*8+j)*HID + t*16+mn], 0 if k>=K.

__device__ void dev_prep(
    const float* __restrict__ wn0, const float* __restrict__ wn1,
    const float* __restrict__ we0, const float* __restrict__ we1,
    const float* __restrict__ cw0, const float* __restrict__ cw1,
    const float* __restrict__ lw0, const float* __restrict__ lw1,
    uint32* __restrict__ wfrag)
{
    for (int idx = threadIdx.x; idx < NSLOT * 64; idx += 256) {
        int s = idx >> 6, lane = idx & 63;
        const float* w; int K, NF, base;
        if (s < 4)       { w = wn0; K = 32; NF = 1; base = S_NW0; }
        else if (s < 12) { w = wn1; K = 64; NF = 2; base = S_NW1; }
        else if (s < 16) { w = we0; K = 16; NF = 1; base = S_EW0; }
        else if (s < 24) { w = we1; K = 64; NF = 2; base = S_EW1; }
        else if (s < 48) { int l = (s - S_CW0) >> 3; w = cw0 + l * 4096; K = 64; NF = 2; base = S_CW0 + l * 8; }
        else if (s < 72) { int l = (s - S_CW1) >> 3; w = cw1 + l * 4096; K = 64; NF = 2; base = S_CW1 + l * 8; }
        else if (s < 80) { w = lw0; K = 64; NF = 2; base = S_LW0; }
        else             { w = lw1; K = 64; NF = 2; base = S_LW1; }
        int r = s - base, t = r / NF, f = r - t * NF;
        int quad = lane >> 4, mn = lane & 15;
        uint32 out[4];
        #pragma unroll
        for (int p = 0; p < 4; p++) {
            int k0 = f * 32 + quad * 8 + p * 2;
            float lo = (k0 < K)     ? w[(size_t)k0 * HID + t * 16 + mn]       : 0.f;
            float hi = (k0 + 1 < K) ? w[(size_t)(k0 + 1) * HID + t * 16 + mn] : 0.f;
            out[p] = pack_bf2(lo, hi);
        }
        *(uint4*)(wfrag + (size_t)idx * 4) = make_uint4(out[0], out[1], out[2], out[3]);
    }
}

__device__ void dev_binA(int* cnt, int* cur, int b,
                         const int* __restrict__ src, const int* __restrict__ dst,
                         int* __restrict__ bcursor, uint2* __restrict__ binned)
{
    const int t = threadIdx.x;
    for (int k = t; k < NBKT; k += 256) cnt[k] = 0;
    __syncthreads();
    const int base = b * 4096;
    #pragma unroll
    for (int j = 0; j < 16; j++) {
        int e = base + j * 256 + t;
        if (e < N_EDGES) atomicAdd(&cnt[dst[e] >> 8], 1);
    }
    __syncthreads();
    for (int k = t; k < NBKT; k += 256) {
        int c = cnt[k];
        cur[k] = (c > 0) ? atomicAdd(&bcursor[(size_t)k * CPAD], c) : 0;
    }
    __syncthreads();
    #pragma unroll
    for (int j = 0; j < 16; j++) {
        int e = base + j * 256 + t;
        if (e < N_EDGES) {
            int d = dst[e];
            int bkt = d >> 8;
            int r = atomicAdd(&cur[bkt], 1);
            if (r < BCAP)
                binned[(size_t)bkt * BCAP + r] =
                    make_uint2((uint32)src[e] | ((uint32)(d & (NPB - 1)) << 17), (uint32)e);
        }
    }
}

__global__ __launch_bounds__(256) void k_prep_binA(
    const int* __restrict__ src, const int* __restrict__ dst,
    int* __restrict__ bcursor, uint2* __restrict__ binned,
    const float* __restrict__ wn0, const float* __restrict__ wn1,
    const float* __restrict__ we0, const float* __restrict__ we1,
    const float* __restrict__ cw0, const float* __restrict__ cw1,
    const float* __restrict__ lw0, const float* __restrict__ lw1,
    uint32* __restrict__ wfrag)
{
    __shared__ int cnt[NBKT];
    __shared__ int cur[NBKT];
    if (blockIdx.x < NBB) dev_binA(cnt, cur, blockIdx.x, src, dst, bcursor, binned);
    else                  dev_prep(wn0, wn1, we0, we1, cw0, cw1, lw0, lw1, wfrag);
}

// ------ merged kernel 2: bucketB w/ inline scan (blocks 0..390) | node-init MLP (rest) ------

__device__ void dev_bucketB(int* cnt, int* shv, int b,
                            const int* __restrict__ bcursor, const uint2* __restrict__ binned,
                            int* __restrict__ rowptr, int* __restrict__ perm_src,
                            int* __restrict__ eperm)
{
    const int t = threadIdx.x;
    // inline exclusive prefix over buckets < b (replaces the 1-block k_scanB launch)
    int s = 0;
    for (int k = t; k < b; k += 256) s += min(bcursor[(size_t)k * CPAD], BCAP);
    shv[t] = s; __syncthreads();
    for (int off = 128; off > 0; off >>= 1) {
        if (t < off) shv[t] += shv[t + off];
        __syncthreads();
    }
    const int base = shv[0];
    const int n = min(bcursor[(size_t)b * CPAD], BCAP);
    const uint2* brec = binned + (size_t)b * BCAP;
    __syncthreads();
    cnt[t] = 0;
    __syncthreads();
    for (int i = t; i < n; i += 256)
        atomicAdd(&cnt[brec[i].x >> 17], 1);
    __syncthreads();
    int c = cnt[t];
    shv[t] = c; __syncthreads();
    for (int off = 1; off < NPB; off <<= 1) {
        int u = (t >= off) ? shv[t - off] : 0;
        __syncthreads();
        shv[t] += u;
        __syncthreads();
    }
    int excl = shv[t] - c;
    int g = b * NPB + t;
    if (g < N_NODES) rowptr[g] = base + excl;
    if (b == 0 && t == 0) rowptr[N_NODES] = N_EDGES;
    cnt[t] = excl;  // becomes per-node cursor
    __syncthreads();
    for (int i = t; i < n; i += 256) {
        uint2 r = brec[i];
        int dl = (int)(r.x >> 17);
        int p = base + atomicAdd(&cnt[dl], 1);
        perm_src[p] = (int)(r.x & 0x1FFFFu);
        eperm[p] = (int)r.y;
    }
}

// node init MLP2 (f32 x -> h f32 + f16 copy). Per-wave LDS tile, no __syncthreads.
__device__ void dev_node_mlp(ushort* T, int blk,
                             const float* __restrict__ x, float* __restrict__ h,
                             const uint32* __restrict__ wf0, const float* __restrict__ b0,
                             const uint32* __restrict__ wf1, const float* __restrict__ b1,
                             uint32* __restrict__ out_bf)
{
    const int lane = threadIdx.x & 63;
    const int quad = lane >> 4, mn = lane & 15;

    bf8 w0f[4];
    #pragma unroll
    for (int t = 0; t < 4; t++)
        w0f[t] = *(const bf8*)(wf0 + ((size_t)t * 64 + lane) * 4);
    bf8 w1f[4][2];
    #pragma unroll
    for (int t = 0; t < 4; t++)
        #pragma unroll
        for (int f = 0; f < 2; f++)
            w1f[t][f] = *(const bf8*)(wf1 + ((size_t)(t * 2 + f) * 64 + lane) * 4);
    float b0v[4], b1v[4];
    #pragma unroll
    for (int t = 0; t < 4; t++) { b0v[t] = b0[t*16+mn]; b1v[t] = b1[t*16+mn]; }

    const int ebase = blk * 64 + (int)(threadIdx.x >> 6) * 16;
    int rowA = min(ebase + mn, N_NODES - 1);
    bf8 a1;
    {
        const float4* pr = (const float4*)(x + (size_t)rowA * INN + quad * 8);
        float4 v0 = pr[0], v1 = pr[1];
        a1[0]=(short)f2bf(v0.x); a1[1]=(short)f2bf(v0.y);
        a1[2]=(short)f2bf(v0.z); a1[3]=(short)f2bf(v0.w);
        a1[4]=(short)f2bf(v1.x); a1[5]=(short)f2bf(v1.y);
        a1[6]=(short)f2bf(v1.z); a1[7]=(short)f2bf(v1.w);
    }
    #pragma unroll
    for (int t = 0; t < 4; t++) {
        f32x4 c = {0.f, 0.f, 0.f, 0.f};
        c = __builtin_amdgcn_mfma_f32_16x16x32_bf16(a1, w0f[t], c, 0, 0, 0);
        #pragma unroll
        for (int rg = 0; rg < 4; rg++) {
            int row = quad * 4 + rg;
            T[row * 72 + t * 16 + mn] = f2bf(fmaxf(c[rg] + b0v[t], 0.f));
        }
    }
    __builtin_amdgcn_wave_barrier();
    bf8 a2[2];
    #pragma unroll
    for (int f = 0; f < 2; f++)
        a2[f] = *(const bf8*)&T[mn * 72 + f * 32 + quad * 8];
    #pragma unroll
    for (int t = 0; t < 4; t++) {
        f32x4 c = {0.f, 0.f, 0.f, 0.f};
        c = __builtin_amdgcn_mfma_f32_16x16x32_bf16(a2[0], w1f[t][0], c, 0, 0, 0);
        c = __builtin_amdgcn_mfma_f32_16x16x32_bf16(a2[1], w1f[t][1], c, 0, 0, 0);
        #pragma unroll
        for (int rg = 0; rg < 4; rg++) {
            int row = quad * 4 + rg;
            int rowg = ebase + row;
            float v = c[rg] + b1v[t];
            if (rowg < N_NODES) h[(size_t)rowg * HID + t * 16 + mn] = v;
            T[row * 72 + t * 16 + mn] = f2h_u(v);  // f16 direct (store path reads raw)
        }
    }
    __builtin_amdgcn_wave_barrier();
    int half = lane >> 5, c32 = lane & 31;
    #pragma unroll
    for (int rr = 0; rr < 8; rr++) {
        int row = rr * 2 + half;
        int pos = ebase + row;
        if (pos < N_NODES)
            out_bf[(size_t)pos * 32 + c32] = *(const uint32*)&T[row * 72 + c32 * 2];
    }
}

__global__ __launch_bounds__(256, 4) void k_build_mlp(
    const int* __restrict__ bcursor, const uint2* __restrict__ binned,
    int* __restrict__ rowptr, int* __restrict__ perm_src, int* __restrict__ eperm,
    const float* __restrict__ x, float* __restrict__ h,
    const uint32* __restrict__ wfrag,
    const float* __restrict__ bn0, const float* __restrict__ bn1,
    uint32* __restrict__ out_bf)
{
    __shared__ int cnt[NPB];
    __shared__ int shv[NPB];
    __shared__ ushort tile[4][16 * 72];
    if (blockIdx.x < NBKT)
        dev_bucketB(cnt, shv, blockIdx.x, bcursor, binned, rowptr, perm_src, eperm);
    else
        dev_node_mlp(&tile[threadIdx.x >> 6][0], blockIdx.x - NBKT, x, h,
                     wfrag + S_NW0 * 256, bn0, wfrag + S_NW1 * 256, bn1, out_bf);
}

// ---------------- edge MLP2 via MFMA: wave-independent 16-row tiles, ----------------
// 2-deep pipelined gather (eattr for t+s, eperm index for t+2s), no barriers.
// (256,4): 48 VGPR fits without spills -- (256,8) forced 32 VGPR and spilled
// weight frags to scratch (R4: FETCH 63->338 MB, 57->161 us). Do not raise.
// Final tile stored as f16 directly (1 v_cvt vs bf-pack+repack).

__global__ __launch_bounds__(256, 4) void k_edge_mlp_mfma(
    const float* __restrict__ eattr, const int* __restrict__ eperm,
    uint32* __restrict__ e_sorted, const uint32* __restrict__ wfrag,
    const float* __restrict__ b0, const float* __restrict__ b1)
{
    __shared__ ushort tile[4][16 * 72];  // per-wave 16 rows x 64 x 2B (+8 pad)
    const int wave = threadIdx.x >> 6, lane = threadIdx.x & 63;
    const int quad = lane >> 4, mn = lane & 15;
    ushort* T = &tile[wave][0];

    bf8 w0f[4];      // layer1 B-frags (K=16 zero-padded, NF=1)
    #pragma unroll
    for (int t = 0; t < 4; t++)
        w0f[t] = *(const bf8*)(wfrag + ((size_t)(S_EW0 + t) * 64 + lane) * 4);
    bf8 w1f[4][2];
    #pragma unroll
    for (int t = 0; t < 4; t++)
        #pragma unroll
        for (int f = 0; f < 2; f++)
            w1f[t][f] = *(const bf8*)(wfrag + ((size_t)(S_EW1 + t * 2 + f) * 64 + lane) * 4);
    float b0v[4], b1v[4];
    #pragma unroll
    for (int t = 0; t < 4; t++) { b0v[t] = b0[t*16+mn]; b1v[t] = b1[t*16+mn]; }

    const int nT = N_EDGES / 16;  // 62500 (exact)
    const int stride = gridDim.x * 4;
    int t = blockIdx.x * 4 + wave;

    int ep0 = (t < nT) ? eperm[t * 16 + mn] : 0;
    int ep1 = (t + stride < nT) ? eperm[(t + stride) * 16 + mn] : 0;
    float4 va = make_float4(0.f,0.f,0.f,0.f), vb = va;
    if (quad < 2 && t < nT) {
        const float4* pr = (const float4*)(eattr + (size_t)ep0 * INE + quad * 8);
        va = pr[0]; vb = pr[1];
    }

    for (; t < nT; t += stride) {
        const int tn = t + stride;
        float4 na = make_float4(0.f,0.f,0.f,0.f), nb = na;
        if (quad < 2 && tn < nT) {
            const float4* pr = (const float4*)(eattr + (size_t)ep1 * INE + quad * 8);
            na = pr[0]; nb = pr[1];
        }
        int ep2 = (t + 2 * stride < nT) ? eperm[(t + 2 * stride) * 16 + mn] : 0;

        bf8 a1 = {};
        if (quad < 2) {
            a1[0]=(short)f2bf(va.x); a1[1]=(short)f2bf(va.y);
            a1[2]=(short)f2bf(va.z); a1[3]=(short)f2bf(va.w);
            a1[4]=(short)f2bf(vb.x); a1[5]=(short)f2bf(vb.y);
            a1[6]=(short)f2bf(vb.z); a1[7]=(short)f2bf(vb.w);
        }
        #pragma unroll
        for (int t4 = 0; t4 < 4; t4++) {
            f32x4 c = {0.f, 0.f, 0.f, 0.f};
            c = __builtin_amdgcn_mfma_f32_16x16x32_bf16(a1, w0f[t4], c, 0, 0, 0);
            #pragma unroll
            for (int rg = 0; rg < 4; rg++) {
                int row = quad * 4 + rg;
                T[row * 72 + t4 * 16 + mn] = f2bf(fmaxf(c[rg] + b0v[t4], 0.f));
            }
        }
        __builtin_amdgcn_wave_barrier();
        bf8 a2[2];
        #pragma unroll
        for (int f = 0; f < 2; f++)
            a2[f] = *(const bf8*)&T[mn * 72 + f * 32 + quad * 8];
        #pragma unroll
        for (int t4 = 0; t4 < 4; t4++) {
            f32x4 c = {0.f, 0.f, 0.f, 0.f};
            c = __builtin_amdgcn_mfma_f32_16x16x32_bf16(a2[0], w1f[t4][0], c, 0, 0, 0);
            c = __builtin_amdgcn_mfma_f32_16x16x32_bf16(a2[1], w1f[t4][1], c, 0, 0, 0);
            #pragma unroll
            for (int rg = 0; rg < 4; rg++) {
                int row = quad * 4 + rg;
                T[row * 72 + t4 * 16 + mn] = f2h_u(c[rg] + b1v[t4]);  // f16 direct
            }
        }
        __builtin_amdgcn_wave_barrier();
        int half = lane >> 5, c32 = lane & 31;
        #pragma unroll
        for (int rr = 0; rr < 8; rr++) {
            int row = rr * 2 + half;
            e_sorted[((size_t)t * 16 + row) * 32 + c32] = *(const uint32*)&T[row * 72 + c32 * 2];
        }
        __builtin_amdgcn_wave_barrier();
        va = na; vb = nb; ep1 = ep2;
    }
}

// ---------------- fused GINE layer: agg (64 nodes/block) + MLP2 via MFMA ----------------
// Agg: the wave's 16 nodes own a CONTIGUOUS slot range -> stage perm_src for the
// whole range into LDS upfront (coalesced), killing the per-node perm L2 round-trip.
// Messages in packed f16 (pk_add/pk_max); z -> LDS bf16 A-frag; MLP via MFMA.
// h (f32) owned by block -> in-place; h_f16 ping-pong across launches.

template<bool RELU_RES, bool BF_OUT>
__global__ __launch_bounds__(256, 4) void k_layer(
    float* __restrict__ h, const uint32* __restrict__ bf_in,
    uint32* __restrict__ bf_out, const uint32* __restrict__ e_sorted,
    const int* __restrict__ rowptr, const int* __restrict__ perm_src,
    const uint32* __restrict__ wf0, const float* __restrict__ b0,
    const uint32* __restrict__ wf1, const float* __restrict__ b1)
{
    __shared__ ushort tile[4][16 * 72];
    __shared__ int pm[4][PMCAP];
    const int wave = threadIdx.x >> 6, lane = threadIdx.x & 63;
    const int quad = lane >> 4, mn = lane & 15;
    const int half = lane >> 5, c = lane & 31;
    ushort* T = &tile[wave][0];

    const int nbase = blockIdx.x * 64 + wave * 16;  // this wave's 16 nodes

    // ---- Phase A: stage perm range, then aggregate 16 nodes -> z into LDS ----
    int rp = rowptr[min(nbase + (int)lane, N_NODES)];
    const int R0w = __shfl(rp, 0), R1w = __shfl(rp, 16);
    const bool fit = (R1w - R0w) <= PMCAP;
    if (fit)
        for (int k = lane; k < R1w - R0w; k += 64) pm[wave][k] = perm_src[R0w + k];

    float2 hn_cur = *(const float2*)&h[(size_t)min(nbase, N_NODES - 1) * HID + 2 * c];
    #pragma unroll 1
    for (int i = 0; i < 16; i++) {
        int r0 = __shfl(rp, i), r1 = __shfl(rp, i + 1);
        float2 hn_nxt = *(const float2*)&h[(size_t)min(nbase + i + 1, N_NODES - 1) * HID + 2 * c];
        uint32 acc = 0u;
        #pragma unroll 1
        for (int base = r0; base < r1; base += 16) {
            int idxs[8], idxc[8], sidx[8];
            #pragma unroll
            for (int j = 0; j < 8; j++) {
                int idx = base + 2 * j + half;
                idxs[j] = idx;
                idxc[j] = (idx < r1) ? idx : (r1 - 1);
            }
            if (fit) {
                #pragma unroll
                for (int j = 0; j < 8; j++) sidx[j] = pm[wave][idxc[j] - R0w];
            } else {
                #pragma unroll
                for (int j = 0; j < 8; j++) sidx[j] = perm_src[idxc[j]];
            }
            uint32 hv[8], ev[8];
            #pragma unroll
            for (int j = 0; j < 8; j++) {
                hv[j] = bf_in[(size_t)sidx[j] * 32 + c];
                ev[j] = e_sorted[(size_t)idxc[j] * 32 + c];
            }
            #pragma unroll
            for (int j = 0; j < 8; j++) {
                uint32 m = pk_max_f16(pk_add_f16(hv[j], ev[j]), 0u);
                m = (idxs[j] < r1) ? m : 0u;
                acc = pk_add_f16(acc, m);
            }
        }
        float accx = h2_lo(acc), accy = h2_hi(acc);
        accx += __shfl_xor(accx, 32);
        accy += __shfl_xor(accy, 32);
        if (half == 0)
            *(uint32*)&T[i * 72 + 2 * c] = pack_bf2(fmaf(1.1f, hn_cur.x, accx),
                                                    fmaf(1.1f, hn_cur.y, accy));
        hn_cur = hn_nxt;
    }
    __builtin_amdgcn_wave_barrier();

    // ---- Phase B: MLP. Weight frags loaded here (after agg) to cap peak VGPR. ----
    bf8 w0f[4][2], w1f[4][2];
    #pragma unroll
    for (int t = 0; t < 4; t++)
        #pragma unroll
        for (int f = 0; f < 2; f++) {
            w0f[t][f] = *(const bf8*)(wf0 + ((size_t)(t * 2 + f) * 64 + lane) * 4);
            w1f[t][f] = *(const bf8*)(wf1 + ((size_t)(t * 2 + f) * 64 + lane) * 4);
        }
    float b0v[4], b1v[4];
    #pragma unroll
    for (int t = 0; t < 4; t++) { b0v[t] = b0[t*16+mn]; b1v[t] = b1[t*16+mn]; }

    bf8 a1[2];
    #pragma unroll
    for (int f = 0; f < 2; f++)
        a1[f] = *(const bf8*)&T[mn * 72 + f * 32 + quad * 8];
    #pragma unroll
    for (int t = 0; t < 4; t++) {
        f32x4 cc = {0.f, 0.f, 0.f, 0.f};
        cc = __builtin_amdgcn_mfma_f32_16x16x32_bf16(a1[0], w0f[t][0], cc, 0, 0, 0);
        cc = __builtin_amdgcn_mfma_f32_16x16x32_bf16(a1[1], w0f[t][1], cc, 0, 0, 0);
        #pragma unroll
        for (int rg = 0; rg < 4; rg++) {
            int row = quad * 4 + rg;
            T[row * 72 + t * 16 + mn] = f2bf(fmaxf(cc[rg] + b0v[t], 0.f));
        }
    }
    __builtin_amdgcn_wave_barrier();
    bf8 a2[2];
    #pragma unroll
    for (int f = 0; f < 2; f++)
        a2[f] = *(const bf8*)&T[mn * 72 + f * 32 + quad * 8];
    #pragma unroll
    for (int t = 0; t < 4; t++) {
        f32x4 cc = {0.f, 0.f, 0.f, 0.f};
        cc = __builtin_amdgcn_mfma_f32_16x16x32_bf16(a2[0], w1f[t][0], cc, 0, 0, 0);
        cc = __builtin_amdgcn_mfma_f32_16x16x32_bf16(a2[1], w1f[t][1], cc, 0, 0, 0);
        #pragma unroll
        for (int rg = 0; rg < 4; rg++) {
            int row = quad * 4 + rg;
            int rowg = nbase + row;
            int rowc = (rowg < N_NODES) ? rowg : (N_NODES - 1);
            float v = cc[rg] + b1v[t];
            if (RELU_RES) {
                float hv = h[(size_t)rowc * HID + t * 16 + mn];
                v = fmaxf(v + hv, 0.f);
            }
            if (rowg < N_NODES) h[(size_t)rowg * HID + t * 16 + mn] = v;
            T[row * 72 + t * 16 + mn] = f2h_u(v);  // f16 direct (only the raw-store reads this)
        }
    }
    if (BF_OUT) {
        __builtin_amdgcn_wave_barrier();
        #pragma unroll
        for (int rr = 0; rr < 8; rr++) {
            int row = rr * 2 + half;
            int pos = nbase + row;
            if (pos < N_NODES)
                bf_out[(size_t)pos * 32 + c] = *(const uint32*)&T[row * 72 + c * 2];
        }
    }
}

// ---------------- global add pool (batch is sorted) ----------------

__global__ __launch_bounds__(256) void k_pool(
    const float* __restrict__ h, const int* __restrict__ batch, float* __restrict__ out)
{
    int g = blockIdx.x;
    int lane = threadIdx.x & 63, wave = threadIdx.x >> 6;
    int lo = 0, hi = N_NODES;
    while (lo < hi) { int mid = (lo + hi) >> 1; if (batch[mid] < g) lo = mid + 1; else hi = mid; }
    int start = lo;
    hi = N_NODES;
    while (lo < hi) { int mid = (lo + hi) >> 1; if (batch[mid] < g + 1) lo = mid + 1; else hi = mid; }
    int end = lo;
    float acc = 0.f;
    for (int n = start + wave; n < end; n += 4)
        acc += h[(size_t)n*HID + lane];
    __shared__ float sh[4][64];
    sh[wave][lane] = acc;
    __syncthreads();
    if (wave == 0)
        out[(size_t)g*HID + lane] = sh[0][lane] + sh[1][lane] + sh[2][lane] + sh[3][lane];
}

// ---------------- launch ----------------

extern "C" void kernel_launch(void* const* d_in, const int* in_sizes, int n_in,
                              void* d_out, int out_size, void* d_ws, size_t ws_size,
                              hipStream_t stream) {
    const float* x     = (const float*)d_in[0];
    const int*   eidx  = (const int*)  d_in[1];
    const float* eattr = (const float*)d_in[2];
    const int*   batch = (const int*)  d_in[3];
    const float* wn0 = (const float*)d_in[4];  const float* bn0 = (const float*)d_in[5];
    const float* wn1 = (const float*)d_in[6];  const float* bn1 = (const float*)d_in[7];
    const float* we0 = (const float*)d_in[8];  const float* be0 = (const float*)d_in[9];
    const float* we1 = (const float*)d_in[10]; const float* be1 = (const float*)d_in[11];
    const float* cw0 = (const float*)d_in[12]; const float* cb0 = (const float*)d_in[13];
    const float* cw1 = (const float*)d_in[14]; const float* cb1 = (const float*)d_in[15];
    const float* lw0 = (const float*)d_in[16]; const float* lb0 = (const float*)d_in[17];
    const float* lw1 = (const float*)d_in[18]; const float* lb1 = (const float*)d_in[19];
    const int* src = eidx;
    const int* dst = eidx + N_EDGES;

    // workspace layout (~200 MB)
    char* ws = (char*)d_ws;
    size_t off = 0;
    auto alloc = [&](size_t bytes) -> void* {
        void* p = ws + off;
        off = (off + bytes + 255) & ~(size_t)255;
        return p;
    };
    int*    bcursor  = (int*)  alloc((size_t)NBKT * CPAD * 4);       // per-bucket claim cursors / counts
    uint2*  binned   = (uint2*)alloc((size_t)NBKT * BCAP * 8);       // 12.8 MB bucket-partitioned records
    int*    rowptr   = (int*)  alloc((size_t)(N_NODES + 1) * 4);
    int*    perm_src = (int*)  alloc((size_t)N_EDGES * 4);
    int*    eperm    = (int*)  alloc((size_t)N_EDGES * 4);           // slot -> original edge id
    float*  h        = (float*)alloc((size_t)N_NODES * HID * 4);
    uint32* bfB      = (uint32*)alloc((size_t)N_NODES * 32 * 4);     // f16 h ping-pong B
    uint32* bfA      = (uint32*)alloc((size_t)N_NODES * 32 * 4);     // f16 h ping-pong A
    uint32* e_sorted = (uint32*)alloc((size_t)N_EDGES * HID * 2);
    uint32* wfrag    = (uint32*)alloc((size_t)NSLOT * 64 * 16);      // pre-converted weight frags
    if (off > ws_size) {
        k_diag<<<1, 64, 0, stream>>>((float*)d_out, 1.0e9f);
        return;
    }

    const int MGRID = (N_NODES + 63) / 64;  // 1563

    // L0: zero bucket cursors
    hipMemsetAsync(bcursor, 0, (size_t)NBKT * CPAD * 4, stream);
    // L1: binA (245 blocks) | weight prep (1 block)
    k_prep_binA<<<NBB + 1, 256, 0, stream>>>(src, dst, bcursor, binned,
                                             wn0, wn1, we0, we1, cw0, cw1, lw0, lw1, wfrag);
    // L2: bucketB w/ inline scan (391) | node-init MLP (1563) -> h + bfA
    k_build_mlp<<<NBKT + MGRID, 256, 0, stream>>>(bcursor, binned, rowptr, perm_src, eperm,
                                                  x, h, wfrag, bn0, bn1, bfA);
    // L3: edge MLP -> e_sorted (dst-sorted order, f16)
    k_edge_mlp_mfma<<<2048, 256, 0, stream>>>(eattr, eperm, e_sorted, wfrag, be0, be1);

    // L4-6: 3 residual conv layers (fused agg+MLP), f16 ping-pong A->B->A->B
    k_layer<true, true><<<MGRID, 256, 0, stream>>>(
        h, bfA, bfB, e_sorted, rowptr, perm_src,
        wfrag + (S_CW0 + 0 * 8) * 256, cb0 + 0 * 64, wfrag + (S_CW1 + 0 * 8) * 256, cb1 + 0 * 64);
    k_layer<true, true><<<MGRID, 256, 0, stream>>>(
        h, bfB, bfA, e_sorted, rowptr, perm_src,
        wfrag + (S_CW0 + 1 * 8) * 256, cb0 + 1 * 64, wfrag + (S_CW1 + 1 * 8) * 256, cb1 + 1 * 64);
    k_layer<true, true><<<MGRID, 256, 0, stream>>>(
        h, bfA, bfB, e_sorted, rowptr, perm_src,
        wfrag + (S_CW0 + 2 * 8) * 256, cb0 + 2 * 64, wfrag + (S_CW1 + 2 * 8) * 256, cb1 + 2 * 64);
    // L7: final GINE conv (no residual/relu, no f16 output)
    k_layer<false, false><<<MGRID, 256, 0, stream>>>(
        h, bfB, bfA, e_sorted, rowptr, perm_src,
        wfrag + S_LW0 * 256, lb0, wfrag + S_LW1 * 256, lb1);

    // L8: global add pool
    k_pool<<<N_GRAPHS, 256, 0, stream>>>(h, batch, (float*)d_out);
}